// Round 3
// baseline (2375.760 us; speedup 1.0000x reference)
//
#include <hip/hip_runtime.h>
#include <hip/hip_bf16.h>

// N=32768 queries, D=256 dims, K=4096 codes (fp32 in/out).
#define VQ_N 32768
#define VQ_D 256
#define VQ_K 4096
#define CAP  32      // candidate list cap per row (overflow -> full rescan)
#define BAND 16.0f   // 2*eps, eps = 2^-7 * 2 * ||x||max * ||c||max <= 7.6

typedef __attribute__((ext_vector_type(8))) short short8;  // 8 bf16 (4 VGPRs)
typedef __attribute__((ext_vector_type(4))) float f32x4;   // MFMA C/D frag

// monotone float<->uint map (total order incl. negatives)
__device__ __forceinline__ unsigned fmap(float f) {
    unsigned b = __float_as_uint(f);
    return (b & 0x80000000u) ? ~b : (b | 0x80000000u);
}
__device__ __forceinline__ float fmapinv(unsigned u) {
    unsigned b = (u & 0x80000000u) ? (u & 0x7FFFFFFFu) : ~u;
    return __uint_as_float(b);
}

// async global->LDS, 16B per lane; lds dest = wave-uniform base + lane*16
__device__ __forceinline__ void async16(const void* g, void* l) {
    __builtin_amdgcn_global_load_lds(
        (const __attribute__((address_space(1))) unsigned int*)g,
        (__attribute__((address_space(3))) unsigned int*)l, 16, 0, 0);
}

// ---------------------------------------------------------------------------
// prep: fp32 -> bf16 conversions (vectorized, 4 elems/thread)
// ---------------------------------------------------------------------------
__global__ __launch_bounds__(256)
void prep_x_kernel(const float* __restrict__ x, __hip_bfloat16* __restrict__ xb) {
    const int i = blockIdx.x * 256 + threadIdx.x;
    const float4 v = reinterpret_cast<const float4*>(x)[i];
    union { __hip_bfloat16 h[4]; short4 s4; } u;
    u.h[0] = __float2bfloat16(v.x); u.h[1] = __float2bfloat16(v.y);
    u.h[2] = __float2bfloat16(v.z); u.h[3] = __float2bfloat16(v.w);
    reinterpret_cast<short4*>(xb)[i] = u.s4;
}

__global__ __launch_bounds__(256)
void prep_cb_kernel(const float* __restrict__ cb, __hip_bfloat16* __restrict__ cbb) {
    const int i = blockIdx.x * 256 + threadIdx.x;
    const float4 v = reinterpret_cast<const float4*>(cb)[i];
    union { __hip_bfloat16 h[4]; short4 s4; } u;
    u.h[0] = __float2bfloat16(-2.0f * v.x); u.h[1] = __float2bfloat16(-2.0f * v.y);
    u.h[2] = __float2bfloat16(-2.0f * v.z); u.h[3] = __float2bfloat16(-2.0f * v.w);
    reinterpret_cast<short4*>(cbb)[i] = u.s4;
}

// codebook squared norms in fp32 (exact part of the score)
__global__ void c2_kernel(const float* __restrict__ cb, float* __restrict__ c2) {
    const int wave = threadIdx.x >> 6;
    const int lane = threadIdx.x & 63;
    const int code = blockIdx.x * 4 + wave;
    const float4 v = *reinterpret_cast<const float4*>(&cb[(size_t)code * VQ_D + lane * 4]);
    float s = v.x * v.x + v.y * v.y + v.z * v.z + v.w * v.w;
    #pragma unroll
    for (int off = 32; off > 0; off >>= 1) s += __shfl_xor(s, off, 64);
    if (lane == 0) c2[code] = s;
}

// ---------------------------------------------------------------------------
// MFMA sweep: 128x128 tile per ct, BK=32, 256 thr = 4 waves (2x2 of 64x64).
// s~ = c2[code] + mfma(xb, -2*cb). MIN phase: per-row min -> rowmin (umapped).
// COLLECT phase: append codes with s~ <= rowmin + BAND.
// Deterministic: both phases produce bitwise-identical s~.
// ---------------------------------------------------------------------------
template<bool COLLECT>
__global__ __launch_bounds__(256)
void sweep_kernel(const __hip_bfloat16* __restrict__ xb,
                  const __hip_bfloat16* __restrict__ cbb,
                  const float* __restrict__ c2,
                  unsigned int* __restrict__ rowmin,
                  int* __restrict__ cnt, int* __restrict__ list) {
    __shared__ __attribute__((aligned(16))) __hip_bfloat16 As[128 * 32];
    __shared__ __attribute__((aligned(16))) __hip_bfloat16 Bs[128 * 32];
    __shared__ unsigned int rowmin_s[128];
    const int t = threadIdx.x;
    const int lane = t & 63, wave = t >> 6;
    const int wr = wave >> 1, wc = wave & 1;       // wave's 64x64 quadrant
    const int fr = lane & 15, kg = lane >> 4;      // frag row/col idx, k-group
    const int rowbase = blockIdx.x * 128;
    const int code0 = blockIdx.y * 1024;
    const int srow = lane >> 2, sg = (lane & 3) * 8;  // staging row/k within chunk

    if (!COLLECT && t < 128) rowmin_s[t] = 0xFFFFFFFFu;

    for (int ct = 0; ct < 8; ++ct) {
        const int cbase = code0 + ct * 128;
        f32x4 acc[4][4];
        #pragma unroll
        for (int m = 0; m < 4; ++m)
            #pragma unroll
            for (int n = 0; n < 4; ++n) acc[m][n] = (f32x4){0.f, 0.f, 0.f, 0.f};

        for (int ks = 0; ks < 8; ++ks) {           // K = 256 = 8 x 32
            const int k0 = ks * 32;
            __syncthreads();                        // LDS safe to overwrite
            #pragma unroll
            for (int i = 0; i < 2; ++i) {
                const int c = wave * 2 + i;         // chunk 0..7 (16 rows each)
                async16(&xb [(size_t)(rowbase + c * 16 + srow) * VQ_D + k0 + sg], &As[c * 512]);
                async16(&cbb[(size_t)(cbase   + c * 16 + srow) * VQ_D + k0 + sg], &Bs[c * 512]);
            }
            __syncthreads();                        // drains vmcnt (compiler emits full drain)

            short8 af[4], bf[4];
            #pragma unroll
            for (int m = 0; m < 4; ++m)
                af[m] = *reinterpret_cast<const short8*>(&As[(wr * 64 + m * 16 + fr) * 32 + kg * 8]);
            #pragma unroll
            for (int n = 0; n < 4; ++n)
                bf[n] = *reinterpret_cast<const short8*>(&Bs[(wc * 64 + n * 16 + fr) * 32 + kg * 8]);
            #pragma unroll
            for (int m = 0; m < 4; ++m)
                #pragma unroll
                for (int n = 0; n < 4; ++n)
                    acc[m][n] = __builtin_amdgcn_mfma_f32_16x16x32_bf16(af[m], bf[n], acc[m][n], 0, 0, 0);
        }

        // epilogue for this 128x128 tile (C/D: col=lane&15, row=(lane>>4)*4+r)
        float c2v[4];
        #pragma unroll
        for (int n = 0; n < 4; ++n) c2v[n] = c2[cbase + wc * 64 + n * 16 + fr];

        #pragma unroll
        for (int m = 0; m < 4; ++m) {
            #pragma unroll
            for (int r = 0; r < 4; ++r) {
                const int lrow = wr * 64 + m * 16 + kg * 4 + r;   // 0..127
                if (COLLECT) {
                    const float thr = fmapinv(rowmin[rowbase + lrow]) + BAND;
                    #pragma unroll
                    for (int n = 0; n < 4; ++n) {
                        const float v = acc[m][n][r] + c2v[n];
                        if (v <= thr) {
                            const int code = cbase + wc * 64 + n * 16 + fr;
                            const int pos = atomicAdd(&cnt[rowbase + lrow], 1);
                            if (pos < CAP) list[(size_t)(rowbase + lrow) * CAP + pos] = code;
                        }
                    }
                } else {
                    float bv = acc[m][0][r] + c2v[0];
                    #pragma unroll
                    for (int n = 1; n < 4; ++n) bv = fminf(bv, acc[m][n][r] + c2v[n]);
                    #pragma unroll
                    for (int off = 1; off < 16; off <<= 1)
                        bv = fminf(bv, __shfl_xor(bv, off, 64));   // 16 lanes share a row
                    if (fr == 0) atomicMin(&rowmin_s[lrow], fmap(bv));
                }
            }
        }
    }
    if (!COLLECT) {
        __syncthreads();
        if (t < 128) atomicMin(&rowmin[rowbase + t], rowmin_s[t]);
    }
}

// ---------------------------------------------------------------------------
// rerank: exact fp32 scores over candidates; gather + ind + commit loss.
// One wave per row. Overflowed rows (cnt > CAP) do a full 4096-code scan.
// ---------------------------------------------------------------------------
__global__ __launch_bounds__(256)
void rerank_kernel(const float* __restrict__ x, const float* __restrict__ cb,
                   const float* __restrict__ c2, const int* __restrict__ cnt,
                   const int* __restrict__ list, float* __restrict__ out,
                   float* __restrict__ ind_out, float* __restrict__ loss_accum) {
    const int wave = threadIdx.x >> 6, lane = threadIdx.x & 63;
    const int row = blockIdx.x * 4 + wave;
    const float4 xv = reinterpret_cast<const float4*>(x)[(size_t)row * 64 + lane];
    const int m = cnt[row];
    const bool full = m > CAP;
    const int M = full ? VQ_K : m;
    float bv = 3.4e38f; int bk = 0x7fffffff;
    for (int i = 0; i < M; ++i) {
        const int k = full ? i : list[(size_t)row * CAP + i];
        const float4 cv = reinterpret_cast<const float4*>(cb)[(size_t)k * 64 + lane];
        float d = fmaf(xv.x, cv.x, fmaf(xv.y, cv.y, fmaf(xv.z, cv.z, xv.w * cv.w)));
        #pragma unroll
        for (int off = 1; off < 64; off <<= 1) d += __shfl_xor(d, off, 64);
        const float s = fmaf(-2.0f, d, c2[k]);
        if (s < bv || (s == bv && k < bk)) { bv = s; bk = k; }   // lowest-index ties
    }
    const float4 qv = reinterpret_cast<const float4*>(cb)[(size_t)bk * 64 + lane];
    reinterpret_cast<float4*>(out)[(size_t)row * 64 + lane] = qv;
    if (lane == 0) ind_out[row] = (float)bk;
    const float dx = qv.x - xv.x, dy = qv.y - xv.y, dz = qv.z - xv.z, dw = qv.w - xv.w;
    float s2 = dx * dx + dy * dy + dz * dz + dw * dw;
    #pragma unroll
    for (int off = 1; off < 64; off <<= 1) s2 += __shfl_xor(s2, off, 64);
    __shared__ float ls[4];
    if (lane == 0) ls[wave] = s2;
    __syncthreads();
    if (threadIdx.x == 0) atomicAdd(loss_accum, ls[0] + ls[1] + ls[2] + ls[3]);
}

__global__ void scale_kernel(const float* __restrict__ loss_accum,
                             float* __restrict__ loss_out) {
    *loss_out = loss_accum[0] * (1.0f / ((float)VQ_N * (float)VQ_D));
}

// ---------------------------------------------------------------------------
// d_out layout: [out N*D | ind N | loss 1]. bf16 x reuses the (dead) front of
// d_out during the sweeps. ws: c2 16K | rowmin 128K | cnt 128K | loss | cbb 2M
// | list 4M  (~6.6 MB total).
// ---------------------------------------------------------------------------
extern "C" void kernel_launch(void* const* d_in, const int* in_sizes, int n_in,
                              void* d_out, int out_size, void* d_ws, size_t ws_size,
                              hipStream_t stream) {
    const float* x  = (const float*)d_in[0];
    const float* cb = (const float*)d_in[1];
    float* out      = (float*)d_out;
    float* ind_out  = out + (size_t)VQ_N * VQ_D;
    float* loss_out = ind_out + VQ_N;

    char* w = (char*)d_ws;
    float*          c2         = (float*)w;                           // 16 KB
    unsigned int*   rowmin     = (unsigned int*)(w + (16 << 10));     // 128 KB
    int*            cnt        = (int*)(w + (144 << 10));             // 128 KB
    float*          loss_accum = (float*)(w + (272 << 10));           // 16 B
    __hip_bfloat16* cbb        = (__hip_bfloat16*)(w + (272 << 10) + 64);   // 2 MB
    int*            list       = (int*)(w + (272 << 10) + 64
                                        + (size_t)VQ_K * VQ_D * 2);   // 4 MB
    __hip_bfloat16* xb = (__hip_bfloat16*)d_out;   // 16 MB, dead until rerank

    hipMemsetAsync(rowmin, 0xFF, (size_t)VQ_N * 4, stream);
    hipMemsetAsync(cnt, 0, (size_t)VQ_N * 4 + 16, stream);            // covers loss_accum

    prep_x_kernel<<<VQ_N * VQ_D / 4 / 256, 256, 0, stream>>>(x, xb);
    prep_cb_kernel<<<VQ_K * VQ_D / 4 / 256, 256, 0, stream>>>(cb, cbb);
    c2_kernel<<<VQ_K / 4, 256, 0, stream>>>(cb, c2);

    dim3 gs(VQ_N / 128, 4);   // 4-way code split, 8 ct tiles of 128 each
    sweep_kernel<false><<<gs, 256, 0, stream>>>(xb, cbb, c2, rowmin, cnt, list);
    sweep_kernel<true ><<<gs, 256, 0, stream>>>(xb, cbb, c2, rowmin, cnt, list);

    rerank_kernel<<<VQ_N / 4, 256, 0, stream>>>(x, cb, c2, cnt, list, out, ind_out, loss_accum);
    scale_kernel<<<1, 1, 0, stream>>>(loss_accum, loss_out);
}

// Round 5
// 509.381 us; speedup vs baseline: 4.6640x; 4.6640x over previous
//
#include <hip/hip_runtime.h>
#include <hip/hip_bf16.h>

// N=32768 queries, D=256 dims, K=4096 codes (fp32 in/out).
#define VQ_N 32768
#define VQ_D 256
#define VQ_K 4096
#define BAND 16.0f              // >= 2 * worst-case bf16 score error (~3.7)
#define QCAP (2u * 1024u * 1024u)  // global queue capacity (u32 entries)
#define BUFCAP 2048             // per-block LDS queue buffer

typedef __attribute__((ext_vector_type(8))) short short8;  // 8 bf16 (4 VGPRs)
typedef __attribute__((ext_vector_type(4))) float f32x4;   // MFMA C/D frag

// monotone float<->uint map (total order incl. negatives)
__device__ __forceinline__ unsigned fmap(float f) {
    unsigned b = __float_as_uint(f);
    return (b & 0x80000000u) ? ~b : (b | 0x80000000u);
}
__device__ __forceinline__ float fmapinv(unsigned u) {
    unsigned b = (u & 0x80000000u) ? (u & 0x7FFFFFFFu) : ~u;
    return __uint_as_float(b);
}

// async global->LDS, 16B per lane; lds dest = wave-uniform base + lane*16
__device__ __forceinline__ void async16(const void* g, void* l) {
    __builtin_amdgcn_global_load_lds(
        (const __attribute__((address_space(1))) unsigned int*)g,
        (__attribute__((address_space(3))) unsigned int*)l, 16, 0, 0);
}

// ---------------------------------------------------------------------------
// prep: fp32 -> bf16 (x plain, cb pre-scaled by -2 so MFMA computes -2*x.c)
// ---------------------------------------------------------------------------
__global__ __launch_bounds__(256)
void prep_x_kernel(const float* __restrict__ x, __hip_bfloat16* __restrict__ xb) {
    const int i = blockIdx.x * 256 + threadIdx.x;
    const float4 v = reinterpret_cast<const float4*>(x)[i];
    union { __hip_bfloat16 h[4]; short4 s4; } u;
    u.h[0] = __float2bfloat16(v.x); u.h[1] = __float2bfloat16(v.y);
    u.h[2] = __float2bfloat16(v.z); u.h[3] = __float2bfloat16(v.w);
    reinterpret_cast<short4*>(xb)[i] = u.s4;
}

__global__ __launch_bounds__(256)
void prep_cb_kernel(const float* __restrict__ cb, __hip_bfloat16* __restrict__ cbb) {
    const int i = blockIdx.x * 256 + threadIdx.x;
    const float4 v = reinterpret_cast<const float4*>(cb)[i];
    union { __hip_bfloat16 h[4]; short4 s4; } u;
    u.h[0] = __float2bfloat16(-2.0f * v.x); u.h[1] = __float2bfloat16(-2.0f * v.y);
    u.h[2] = __float2bfloat16(-2.0f * v.z); u.h[3] = __float2bfloat16(-2.0f * v.w);
    reinterpret_cast<short4*>(cbb)[i] = u.s4;
}

// codebook squared norms in fp32 (exact part of the score)
__global__ void c2_kernel(const float* __restrict__ cb, float* __restrict__ c2) {
    const int wave = threadIdx.x >> 6;
    const int lane = threadIdx.x & 63;
    const int code = blockIdx.x * 4 + wave;
    const float4 v = *reinterpret_cast<const float4*>(&cb[(size_t)code * VQ_D + lane * 4]);
    float s = v.x * v.x + v.y * v.y + v.z * v.z + v.w * v.w;
    #pragma unroll
    for (int off = 32; off > 0; off >>= 1) s += __shfl_xor(s, off, 64);
    if (lane == 0) c2[code] = s;
}

// ---------------------------------------------------------------------------
// MFMA sweep: 128x128 tile per ct, BK=32, 4 waves (2x2 of 64x64).
// s~ = c2[code] + mfma(xb, -2*cb).  MIN phase: per-row min -> rowmin (umapped).
// COLLECT phase: append (row,code) with s~ <= rowmin + BAND to a global queue
// via a per-block LDS buffer. Both phases compute bitwise-identical s~.
// ---------------------------------------------------------------------------
template<bool COLLECT>
__global__ __launch_bounds__(256)
void sweep_kernel(const __hip_bfloat16* __restrict__ xb,
                  const __hip_bfloat16* __restrict__ cbb,
                  const float* __restrict__ c2,
                  unsigned int* __restrict__ rowmin,
                  unsigned int* __restrict__ qcnt,
                  unsigned int* __restrict__ overflow,
                  unsigned int* __restrict__ queue) {
    __shared__ __attribute__((aligned(16))) __hip_bfloat16 As[128 * 32];
    __shared__ __attribute__((aligned(16))) __hip_bfloat16 Bs[128 * 32];
    __shared__ unsigned int rowmin_s[128];   // MIN phase
    __shared__ float        thr_s[128];      // COLLECT phase
    __shared__ unsigned int qbuf[BUFCAP];    // COLLECT phase
    __shared__ int qn_s, qbase_s;
    const int t = threadIdx.x;
    const int lane = t & 63, wave = t >> 6;
    const int wr = wave >> 1, wc = wave & 1;       // wave's 64x64 quadrant
    const int fr = lane & 15, kg = lane >> 4;      // frag col idx, k/row group
    const int rowbase = blockIdx.x * 128;
    const int code0 = blockIdx.y * 1024;
    const int srow = lane >> 2, sg = (lane & 3) * 8;  // staging row/k in chunk

    if (COLLECT) {
        if (t < 128) thr_s[t] = fmapinv(rowmin[rowbase + t]) + BAND;
        if (t == 0) qn_s = 0;
    } else {
        if (t < 128) rowmin_s[t] = 0xFFFFFFFFu;
    }
    // (no barrier needed: first use is after the ks-loop's barriers)

    for (int ct = 0; ct < 8; ++ct) {
        const int cbase = code0 + ct * 128;
        f32x4 acc[4][4];
        #pragma unroll
        for (int m = 0; m < 4; ++m)
            #pragma unroll
            for (int n = 0; n < 4; ++n) acc[m][n] = (f32x4){0.f, 0.f, 0.f, 0.f};

        for (int ks = 0; ks < 8; ++ks) {           // K = 256 = 8 x 32
            const int k0 = ks * 32;
            __syncthreads();                        // LDS safe to overwrite
            #pragma unroll
            for (int i = 0; i < 2; ++i) {
                const int c = wave * 2 + i;         // chunk 0..7 (16 rows each)
                async16(&xb [(size_t)(rowbase + c * 16 + srow) * VQ_D + k0 + sg], &As[c * 512]);
                async16(&cbb[(size_t)(cbase   + c * 16 + srow) * VQ_D + k0 + sg], &Bs[c * 512]);
            }
            __syncthreads();                        // vmcnt(0) drain by compiler

            short8 af[4], bf[4];
            #pragma unroll
            for (int m = 0; m < 4; ++m)
                af[m] = *reinterpret_cast<const short8*>(&As[(wr * 64 + m * 16 + fr) * 32 + kg * 8]);
            #pragma unroll
            for (int n = 0; n < 4; ++n)
                bf[n] = *reinterpret_cast<const short8*>(&Bs[(wc * 64 + n * 16 + fr) * 32 + kg * 8]);
            #pragma unroll
            for (int m = 0; m < 4; ++m)
                #pragma unroll
                for (int n = 0; n < 4; ++n)
                    acc[m][n] = __builtin_amdgcn_mfma_f32_16x16x32_bf16(af[m], bf[n], acc[m][n], 0, 0, 0);
        }

        // epilogue (C/D: col=lane&15, row=(lane>>4)*4+r)
        float c2v[4];
        #pragma unroll
        for (int n = 0; n < 4; ++n) c2v[n] = c2[cbase + wc * 64 + n * 16 + fr];

        #pragma unroll
        for (int m = 0; m < 4; ++m) {
            #pragma unroll
            for (int r = 0; r < 4; ++r) {
                const int lrow = wr * 64 + m * 16 + kg * 4 + r;   // 0..127
                if (COLLECT) {
                    const float thr = thr_s[lrow];
                    #pragma unroll
                    for (int n = 0; n < 4; ++n) {
                        const float v = acc[m][n][r] + c2v[n];
                        if (v <= thr) {
                            const int code = cbase + wc * 64 + n * 16 + fr;
                            const int pos = atomicAdd(&qn_s, 1);
                            if (pos < BUFCAP)
                                qbuf[pos] = ((unsigned)(rowbase + lrow) << 12) | (unsigned)code;
                        }
                    }
                } else {
                    float bv = acc[m][0][r] + c2v[0];
                    #pragma unroll
                    for (int n = 1; n < 4; ++n) bv = fminf(bv, acc[m][n][r] + c2v[n]);
                    #pragma unroll
                    for (int off = 1; off < 16; off <<= 1)
                        bv = fminf(bv, __shfl_xor(bv, off, 64));   // 16 lanes share a row
                    if (fr == 0) atomicMin(&rowmin_s[lrow], fmap(bv));
                }
            }
        }
    }
    __syncthreads();
    if (COLLECT) {
        if (t == 0) {
            int n = qn_s;
            if (n > BUFCAP) { atomicOr(overflow, 1u); n = BUFCAP; }
            qbase_s = (int)atomicAdd(qcnt, (unsigned)n);
            qn_s = n;
        }
        __syncthreads();
        const unsigned base = (unsigned)qbase_s;
        for (int i = t; i < qn_s; i += 256) {
            const unsigned p = base + (unsigned)i;
            if (p < QCAP) queue[p] = qbuf[i];      // drops beyond QCAP -> qcnt>QCAP triggers fullscan
        }
    } else {
        if (t < 128) atomicMin(&rowmin[rowbase + t], rowmin_s[t]);
    }
}

// ---------------------------------------------------------------------------
// queue rerank: one WAVE per queue entry (grid-stride). Exact fp32 score,
// atomicMin on (fmap(score)<<32)|code  -> lowest-index tie-break. No per-row
// serial loop can exist: a fat row is just more independent entries.
// ---------------------------------------------------------------------------
__global__ __launch_bounds__(256)
void qrerank_kernel(const float* __restrict__ x, const float* __restrict__ cb,
                    const float* __restrict__ c2,
                    const unsigned int* __restrict__ qcnt,
                    const unsigned int* __restrict__ queue,
                    unsigned long long* __restrict__ keys) {
    const int wave = threadIdx.x >> 6, lane = threadIdx.x & 63;
    unsigned total = *qcnt;
    if (total > QCAP) total = QCAP;
    const unsigned stride = gridDim.x * 4;
    for (unsigned e = blockIdx.x * 4 + wave; e < total; e += stride) {
        const unsigned ent = queue[e];
        const int row = (int)(ent >> 12);
        const int code = (int)(ent & 0xFFFu);
        const float4 xv = reinterpret_cast<const float4*>(x)[(size_t)row * 64 + lane];
        const float4 cv = reinterpret_cast<const float4*>(cb)[(size_t)code * 64 + lane];
        float d = fmaf(xv.x, cv.x, fmaf(xv.y, cv.y, fmaf(xv.z, cv.z, xv.w * cv.w)));
        #pragma unroll
        for (int off = 1; off < 64; off <<= 1) d += __shfl_xor(d, off, 64);
        const float s = fmaf(-2.0f, d, c2[code]);
        if (lane == 0)
            atomicMin(&keys[row],
                      ((unsigned long long)fmap(s) << 32) | (unsigned)code);
    }
}

// ---------------------------------------------------------------------------
// overflow fallback: full exact scan, only if the queue overflowed (~never).
// Uniform predicate -> immediate exit in the normal case.
// ---------------------------------------------------------------------------
__global__ __launch_bounds__(256)
void fullscan_kernel(const float* __restrict__ x, const float* __restrict__ cb,
                     const float* __restrict__ c2,
                     const unsigned int* __restrict__ qcnt,
                     const unsigned int* __restrict__ overflow,
                     unsigned long long* __restrict__ keys) {
    if (*qcnt <= QCAP && *overflow == 0) return;
    const int wave = threadIdx.x >> 6, lane = threadIdx.x & 63;
    for (int row = blockIdx.x * 4 + wave; row < VQ_N; row += gridDim.x * 4) {
        const float4 xv = reinterpret_cast<const float4*>(x)[(size_t)row * 64 + lane];
        float bv = 3.4e38f; int bk = 0;
        for (int k = 0; k < VQ_K; ++k) {
            const float4 cv = reinterpret_cast<const float4*>(cb)[(size_t)k * 64 + lane];
            float d = fmaf(xv.x, cv.x, fmaf(xv.y, cv.y, fmaf(xv.z, cv.z, xv.w * cv.w)));
            #pragma unroll
            for (int off = 1; off < 64; off <<= 1) d += __shfl_xor(d, off, 64);
            const float s = fmaf(-2.0f, d, c2[k]);
            if (s < bv) { bv = s; bk = k; }
        }
        if (lane == 0)
            atomicMin(&keys[row],
                      ((unsigned long long)fmap(bv) << 32) | (unsigned)bk);
    }
}

// ---------------------------------------------------------------------------
// finalize: one wave per row (round-2-proven shape). keys -> ind, gather,
// commitment loss partials.
// ---------------------------------------------------------------------------
__global__ __launch_bounds__(256)
void finalize_kernel(const float* __restrict__ x, const float* __restrict__ cb,
                     const unsigned long long* __restrict__ keys,
                     float* __restrict__ out, float* __restrict__ ind_out,
                     float* __restrict__ loss_accum) {
    const int wave = threadIdx.x >> 6, lane = threadIdx.x & 63;
    const int row = blockIdx.x * 4 + wave;
    const int code = (int)(keys[row] & 0xFFFFFFFFull);
    const float4 qv = reinterpret_cast<const float4*>(cb)[(size_t)code * 64 + lane];
    const float4 xv = reinterpret_cast<const float4*>(x)[(size_t)row * 64 + lane];
    reinterpret_cast<float4*>(out)[(size_t)row * 64 + lane] = qv;
    if (lane == 0) ind_out[row] = (float)code;
    const float dx = qv.x - xv.x, dy = qv.y - xv.y, dz = qv.z - xv.z, dw = qv.w - xv.w;
    float s = dx * dx + dy * dy + dz * dz + dw * dw;
    #pragma unroll
    for (int off = 1; off < 64; off <<= 1) s += __shfl_xor(s, off, 64);
    __shared__ float ls[4];
    if (lane == 0) ls[wave] = s;
    __syncthreads();
    if (threadIdx.x == 0) atomicAdd(loss_accum, ls[0] + ls[1] + ls[2] + ls[3]);
}

__global__ void scale_kernel(const float* __restrict__ loss_accum,
                             float* __restrict__ loss_out) {
    *loss_out = loss_accum[0] * (1.0f / ((float)VQ_N * (float)VQ_D));
}

// ---------------------------------------------------------------------------
// d_out: [out N*D | ind N | loss 1] (33.7 MB). Dead-until-finalize regions
// host bf16 x (d_out[0,16MB)) and the queue (d_out[16MB,24MB)).
// ws: c2 16K | rowmin 128K | keys 256K | qcnt/overflow/loss 64B | cbb 2MB.
// ---------------------------------------------------------------------------
extern "C" void kernel_launch(void* const* d_in, const int* in_sizes, int n_in,
                              void* d_out, int out_size, void* d_ws, size_t ws_size,
                              hipStream_t stream) {
    const float* x  = (const float*)d_in[0];
    const float* cb = (const float*)d_in[1];
    float* out      = (float*)d_out;
    float* ind_out  = out + (size_t)VQ_N * VQ_D;
    float* loss_out = ind_out + VQ_N;

    char* w = (char*)d_ws;
    float*              c2         = (float*)w;                        // 16 KB
    unsigned int*       rowmin     = (unsigned int*)(w + 16384);       // 128 KB
    unsigned long long* keys       = (unsigned long long*)(w + 147456);// 256 KB
    unsigned int*       qcnt       = (unsigned int*)(w + 409600);
    unsigned int*       overflow   = (unsigned int*)(w + 409604);
    float*              loss_accum = (float*)(w + 409608);
    __hip_bfloat16*     cbb        = (__hip_bfloat16*)(w + 409664);    // 2 MB

    __hip_bfloat16* xb    = (__hip_bfloat16*)d_out;                    // 16 MB
    unsigned int*   queue = (unsigned int*)((char*)d_out + (16u << 20)); // 8 MB

    hipMemsetAsync(rowmin, 0xFF, (size_t)VQ_N * 4, stream);
    hipMemsetAsync(keys,   0xFF, (size_t)VQ_N * 8, stream);
    hipMemsetAsync(qcnt,   0,    64, stream);   // qcnt, overflow, loss_accum

    prep_x_kernel <<<VQ_N * VQ_D / 4 / 256, 256, 0, stream>>>(x, xb);
    prep_cb_kernel<<<VQ_K * VQ_D / 4 / 256, 256, 0, stream>>>(cb, cbb);
    c2_kernel     <<<VQ_K / 4, 256, 0, stream>>>(cb, c2);

    dim3 gs(VQ_N / 128, 4);   // 4-way code split, 8 ct tiles of 128 each
    sweep_kernel<false><<<gs, 256, 0, stream>>>(xb, cbb, c2, rowmin, qcnt, overflow, queue);
    sweep_kernel<true ><<<gs, 256, 0, stream>>>(xb, cbb, c2, rowmin, qcnt, overflow, queue);

    qrerank_kernel <<<1024, 256, 0, stream>>>(x, cb, c2, qcnt, queue, keys);
    fullscan_kernel<<<512,  256, 0, stream>>>(x, cb, c2, qcnt, overflow, keys);

    finalize_kernel<<<VQ_N / 4, 256, 0, stream>>>(x, cb, keys, out, ind_out, loss_accum);
    scale_kernel<<<1, 1, 0, stream>>>(loss_accum, loss_out);
}